// Round 1
// 263.442 us; speedup vs baseline: 1.0295x; 1.0295x over previous
//
#include <hip/hip_runtime.h>

// MultiCamNoiseCropV3Prompter: out = x + prompt broadcast over T frames.
// R3: single fused kernel, TGRP=4 frames per thread.
//   - R2 (two-kernel) billed 271 us while neither dispatch exceeded 92 us in
//     rocprof => launch/serialization + prompt round-trip overhead dominates.
//   - R1 fused (T=16/thread) was latency-bound: 588 blocks = ~9 waves/CU.
//     TGRP=4 gives 2352 blocks (~32 waves/CU) and 4 independent float4 loads
//     in flight per thread; prompt recomputed in regs (VALU, hidden).
//   - Non-temporal on x/out (streaming, no reuse) keeps pads L2-resident.

#define PP 30
#define SS 224
#define CROPC 164
#define BB 16
#define TT 16
#define TGRP 4

typedef float f4 __attribute__((ext_vector_type(4)));

__device__ __forceinline__ void interp1d(float pos, float in_size, int in_size_i,
                                         int out_size, int& i0, int& i1, float& w) {
    float scale = in_size / (float)out_size;
    float f = fmaxf((pos + 0.5f) * scale - 0.5f, 0.0f);
    i0 = (int)floorf(f);
    w = f - (float)i0;
    i1 = min(i0 + 1, in_size_i - 1);
}

__global__ void __launch_bounds__(256)
fused4_kernel(const float* __restrict__ x,
              const float* __restrict__ pu,   // [3,3,2P,S]
              const float* __restrict__ pd,   // [3,3,P,S]
              const float* __restrict__ pl,   // [3,3,CROP,2P]
              const float* __restrict__ pr,   // [3,3,CROP,P]
              const int* __restrict__ cam_views,
              const int* __restrict__ offs_r,
              const int* __restrict__ offs_d,
              float* __restrict__ out) {
    const int J4 = SS / 4;  // 56
    const int NG = TT / TGRP;  // 4 frame-groups
    int idx = blockIdx.x * blockDim.x + threadIdx.x;
    const int total = BB * 3 * NG * SS * J4;  // 602,112 = 2352 * 256 exactly
    if (idx >= total) return;

    // idx = (((b*3 + c)*NG + tg)*SS + i)*J4 + j4  -- j4 fastest => coalesced
    int j4 = idx % J4;
    int tmp = idx / J4;
    int i = tmp % SS;
    tmp /= SS;
    int tg = tmp % NG;
    tmp /= NG;
    int c = tmp % 3;
    int b = tmp / 3;

    const int j0 = j4 * 4;

    // ---- issue the 4 streaming x loads FIRST; prompt VALU hides under them.
    size_t base = (((size_t)(b * 3 + c) * TT + (size_t)tg * TGRP) * (SS * SS))
                  + (size_t)i * SS + j0;
    f4 xv[TGRP];
    #pragma unroll
    for (int k = 0; k < TGRP; k++)
        xv[k] = __builtin_nontemporal_load(
            reinterpret_cast<const f4*>(x + base + (size_t)k * (SS * SS)));

    // ---- prompt value for (b, c, i, j0..j0+3), computed in registers.
    const int cam = cam_views[b];
    const int off_r = offs_r[b];
    const int off_d = offs_d[b];
    const int off_l = 2 * PP - off_r;
    const int off_u = 2 * PP - off_d;

    const float* puc = pu + (size_t)(cam * 3 + c) * (2 * PP) * SS;
    const float* pdc = pd + (size_t)(cam * 3 + c) * PP * SS;
    const float* plc = pl + (size_t)(cam * 3 + c) * CROPC * (2 * PP);
    const float* prc = pr + (size_t)(cam * 3 + c) * CROPC * PP;

    float pv[4];
    if (i < off_u) {
        int r0, r1; float w;
        interp1d((float)i, (float)(2 * PP), 2 * PP, off_u, r0, r1, w);
        const float* a  = puc + (size_t)r0 * SS + j0;
        const float* bp = puc + (size_t)r1 * SS + j0;
        #pragma unroll
        for (int k = 0; k < 4; k++)
            pv[k] = a[k] * (1.0f - w) + bp[k] * w;
    } else if (i >= SS - off_d) {
        int r0, r1; float w;
        interp1d((float)(i - (SS - off_d)), (float)PP, PP, off_d, r0, r1, w);
        const float* a  = pdc + (size_t)r0 * SS + j0;
        const float* bp = pdc + (size_t)r1 * SS + j0;
        #pragma unroll
        for (int k = 0; k < 4; k++)
            pv[k] = a[k] * (1.0f - w) + bp[k] * w;
    } else {
        const int r = i - off_u;
        const float* plr = plc + (size_t)r * (2 * PP);
        const float* prr = prc + (size_t)r * PP;
        #pragma unroll
        for (int k = 0; k < 4; k++) {
            int j = j0 + k;
            float v = 0.0f;
            if (j < off_l) {
                int c0, c1; float w;
                interp1d((float)j, (float)(2 * PP), 2 * PP, off_l, c0, c1, w);
                v = plr[c0] * (1.0f - w) + plr[c1] * w;
            } else if (j >= SS - off_r) {
                int c0, c1; float w;
                interp1d((float)(j - (SS - off_r)), (float)PP, PP, off_r, c0, c1, w);
                v = prr[c0] * (1.0f - w) + prr[c1] * w;
            }
            pv[k] = v;
        }
    }

    // ---- add + streaming stores.
    #pragma unroll
    for (int k = 0; k < TGRP; k++) {
        f4 ov = xv[k];
        ov[0] += pv[0];
        ov[1] += pv[1];
        ov[2] += pv[2];
        ov[3] += pv[3];
        __builtin_nontemporal_store(
            ov, reinterpret_cast<f4*>(out + base + (size_t)k * (SS * SS)));
    }
}

extern "C" void kernel_launch(void* const* d_in, const int* in_sizes, int n_in,
                              void* d_out, int out_size, void* d_ws, size_t ws_size,
                              hipStream_t stream) {
    const float* x  = (const float*)d_in[0];
    const float* pu = (const float*)d_in[1];
    const float* pd = (const float*)d_in[2];
    const float* pl = (const float*)d_in[3];
    const float* pr = (const float*)d_in[4];
    const int* cam  = (const int*)d_in[5];
    const int* orr  = (const int*)d_in[6];
    const int* od   = (const int*)d_in[7];
    float* out = (float*)d_out;

    const int total = BB * 3 * (TT / TGRP) * SS * (SS / 4);  // 602,112
    fused4_kernel<<<(total + 255) / 256, 256, 0, stream>>>(
        x, pu, pd, pl, pr, cam, orr, od, out);
}